// Round 1
// baseline (3370.657 us; speedup 1.0000x reference)
//
#include <hip/hip_runtime.h>

#define EPS 1e-5f

__device__ __forceinline__ float fast_rcp(float x) { return __builtin_amdgcn_rcpf(x); }
__device__ __forceinline__ float sigm(float x) { return fast_rcp(1.f + __expf(-x)); }
__device__ __forceinline__ float tanh_fast(float x) { return 1.f - 2.f * fast_rcp(1.f + __expf(2.f * x)); }

// ---------------------------------------------------------------------------
// Kernel AB: per image (BN=2048 blocks), fused
//   conv1(3->16,4x4,s4)+bias+bn+relu+pool3  -> LDS [16][12][12]
//   conv2(16->1,4x4,s4)+bias+bn+relu+pool3  -> c[img] scalar
// Each input byte of x is read exactly once (non-overlapping patches).
// ---------------------------------------------------------------------------
__global__ __launch_bounds__(192) void kAB(
    const float* __restrict__ x,
    const float* __restrict__ w1, const float* __restrict__ cb1,
    const float* __restrict__ g1, const float* __restrict__ b1,
    const float* __restrict__ m1, const float* __restrict__ v1,
    const float* __restrict__ w2, const float* __restrict__ cb2,
    const float* __restrict__ g2, const float* __restrict__ b2,
    const float* __restrict__ m2, const float* __restrict__ v2,
    float* __restrict__ c)
{
    __shared__ float4 w4[16][12];      // conv1 weights [co][ci*4+ky] as float4 over kx
    __shared__ float sc[16], sh[16];   // folded bn1 scale/shift (conv bias folded in)
    __shared__ float plds[16 * 12 * 12];

    const int tid = threadIdx.x;
    const int img = blockIdx.x;

    if (tid < 16) {
        float s = g1[tid] * rsqrtf(v1[tid] + EPS);
        sc[tid] = s;
        sh[tid] = b1[tid] + (cb1[tid] - m1[tid]) * s;
    }
    // 768 weight floats = 192 float4
    ((float4*)w4)[tid] = ((const float4*)w1)[tid];
    __syncthreads();

    if (tid < 144) {
        const int py = tid / 12, px = tid - py * 12;
        const float* xb = x + (size_t)img * 62208;  // 3*144*144
        float pool[16];
#pragma unroll
        for (int co = 0; co < 16; ++co) pool[co] = 0.f;  // relu outputs are >= 0

#pragma unroll
        for (int ppy = 0; ppy < 3; ++ppy) {
#pragma unroll
            for (int ppx = 0; ppx < 3; ++ppx) {
                float4 patch[12];
                const int y0 = py * 12 + ppy * 4;
                const int x0 = px * 12 + ppx * 4;
#pragma unroll
                for (int ci = 0; ci < 3; ++ci)
#pragma unroll
                    for (int dy = 0; dy < 4; ++dy)
                        patch[ci * 4 + dy] =
                            *(const float4*)(xb + ci * 20736 + (y0 + dy) * 144 + x0);
#pragma unroll
                for (int co = 0; co < 16; ++co) {
                    float s = 0.f;
#pragma unroll
                    for (int q = 0; q < 12; ++q) {
                        float4 pw = w4[co][q];
                        float4 pp = patch[q];
                        s = fmaf(pp.x, pw.x, s);
                        s = fmaf(pp.y, pw.y, s);
                        s = fmaf(pp.z, pw.z, s);
                        s = fmaf(pp.w, pw.w, s);
                    }
                    float val = fmaxf(fmaf(s, sc[co], sh[co]), 0.f);
                    pool[co] = fmaxf(pool[co], val);
                }
            }
        }
#pragma unroll
        for (int co = 0; co < 16; ++co) plds[co * 144 + tid] = pool[co];
    }
    __syncthreads();

    // Stage B on wave 0: conv2 over LDS tile. lane = (ch, dy)
    if (tid < 64) {
        const int ch = tid >> 2, dy = tid & 3;
        const float4 wv = *(const float4*)(w2 + ch * 16 + dy * 4);
        const float scale = g2[0] * rsqrtf(v2[0] + EPS);
        const float shift = b2[0] + (cb2[0] - m2[0]) * scale;
        float best = 0.f;
#pragma unroll
        for (int oy = 0; oy < 3; ++oy)
#pragma unroll
            for (int ox = 0; ox < 3; ++ox) {
                const float* ab = plds + ch * 144 + (4 * oy + dy) * 12 + 4 * ox;
                float s = ab[0] * wv.x + ab[1] * wv.y + ab[2] * wv.z + ab[3] * wv.w;
#pragma unroll
                for (int off = 32; off >= 1; off >>= 1) s += __shfl_xor(s, off);
                float val = fmaxf(fmaf(s, scale, shift), 0.f);
                best = fmaxf(best, val);
            }
        if (tid == 0) c[img] = best;
    }
}

// ---------------------------------------------------------------------------
// Kernel C: gating MLP + argmax -> expert index p[32]. One wave, thread=sample.
// ---------------------------------------------------------------------------
__global__ __launch_bounds__(64) void kC(
    const float* __restrict__ c,
    const float* __restrict__ w1, const float* __restrict__ b1,
    const float* __restrict__ w2, const float* __restrict__ b2,
    const float* __restrict__ w3, const float* __restrict__ b3,
    int* __restrict__ p)
{
    const int b = threadIdx.x;
    if (b >= 32) return;
    const float* cb = c + b * 64;
    float h1[32];
#pragma unroll
    for (int j = 0; j < 32; ++j) {
        float s = b1[j];
        for (int i = 0; i < 64; ++i) s = fmaf(w1[j * 64 + i], cb[i], s);
        h1[j] = tanhf(s);
    }
    float h2[32];
#pragma unroll
    for (int j = 0; j < 32; ++j) {
        float s = b2[j];
#pragma unroll
        for (int i = 0; i < 32; ++i) s = fmaf(w2[j * 32 + i], h1[i], s);
        h2[j] = tanhf(s);
    }
    float best = -3.4e38f;
    int bi = 0;
#pragma unroll
    for (int j = 0; j < 6; ++j) {
        float s = b3[j];
#pragma unroll
        for (int i = 0; i < 32; ++i) s = fmaf(w3[j * 32 + i], h2[i], s);
        if (s > best) { best = s; bi = j; }  // strict > == first-max (jnp.argmax)
    }
    p[b] = bi;
}

// ---------------------------------------------------------------------------
// Kernel D: per-expert LSTM chain. 6 blocks x 1 wave. lane holds gate rows
// lane (i/f region) and lane+64 (g/o region); h broadcast via __shfl, no LDS.
// Chains samples b (ascending) with p[b]==e through hreg (hn_tab semantics).
// Fuses the final projection r @ out_w.T + out_b.
// ---------------------------------------------------------------------------
__global__ __launch_bounds__(64) void kD(
    const float* __restrict__ c, const int* __restrict__ p,
    const float* __restrict__ wih, const float* __restrict__ whh,
    const float* __restrict__ bih, const float* __restrict__ bhh,
    const float* __restrict__ hn0,
    const float* __restrict__ ow, const float* __restrict__ obias,
    float* __restrict__ out)
{
    const int e = blockIdx.x;
    const int lane = threadIdx.x;  // 0..63
    const int r0 = lane, r1 = lane + 64;
    const float* we = whh + e * 4096;  // [128][32]
    float w0[32], w1r[32];
#pragma unroll
    for (int k = 0; k < 32; ++k) {
        w0[k] = we[r0 * 32 + k];
        w1r[k] = we[r1 * 32 + k];
    }
    const float wi0 = wih[e * 128 + r0], wi1 = wih[e * 128 + r1];
    const float bs0 = bih[e * 128 + r0] + bhh[e * 128 + r0];
    const float bs1 = bih[e * 128 + r1] + bhh[e * 128 + r1];
    float hreg = (lane < 32) ? hn0[e * 32 + lane] : 0.f;  // chain state

    for (int b = 0; b < 32; ++b) {
        if (p[b] != e) continue;  // wave-uniform branch
        float cvec = c[b * 64 + lane];
        float ccreg = 0.f;   // cell state resets per sample (zeros_like(h0))
        float rvec = 0.f;    // lane t will hold r_t = h_t[31]
        for (int t = 0; t < 64; ++t) {
            const float xt = __shfl(cvec, t);
            float acc0 = fmaf(wi0, xt, bs0);
            float acc1 = fmaf(wi1, xt, bs1);
#pragma unroll
            for (int k = 0; k < 32; ++k) {
                const float hk = __shfl(hreg, k);
                acc0 = fmaf(w0[k], hk, acc0);
                acc1 = fmaf(w1r[k], hk, acc1);
            }
            // lane<32: acc0=i_row, acc1=g_row; lane+32 holds f_row/o_row
            const float fg_in = __shfl_xor(acc0, 32);
            const float og_in = __shfl_xor(acc1, 32);
            const float ig = sigm(acc0);
            const float gg = tanh_fast(acc1);
            const float fg = sigm(fg_in);
            const float og = sigm(og_in);
            ccreg = fmaf(fg, ccreg, ig * gg);
            hreg = og * tanh_fast(ccreg);  // valid on lanes<32 (only those are read)
            const float h31 = __shfl(hreg, 31);
            rvec = (lane == t) ? h31 : rvec;
        }
        // out[b] = r_b @ out_w.T + out_b
#pragma unroll
        for (int a = 0; a < 6; ++a) {
            float tsum = rvec * ow[a * 64 + lane];
#pragma unroll
            for (int off = 32; off >= 1; off >>= 1) tsum += __shfl_xor(tsum, off);
            if (lane == 0) out[b * 6 + a] = tsum + obias[a];
        }
    }
}

extern "C" void kernel_launch(void* const* d_in, const int* in_sizes, int n_in,
                              void* d_out, int out_size, void* d_ws, size_t ws_size,
                              hipStream_t stream)
{
    const float* x    = (const float*)d_in[0];
    const float* c1w  = (const float*)d_in[1];
    const float* c1b  = (const float*)d_in[2];
    const float* bn1g = (const float*)d_in[3];
    const float* bn1b = (const float*)d_in[4];
    const float* bn1m = (const float*)d_in[5];
    const float* bn1v = (const float*)d_in[6];
    const float* c2w  = (const float*)d_in[7];
    const float* c2b  = (const float*)d_in[8];
    const float* bn2g = (const float*)d_in[9];
    const float* bn2b = (const float*)d_in[10];
    const float* bn2m = (const float*)d_in[11];
    const float* bn2v = (const float*)d_in[12];
    const float* pw1  = (const float*)d_in[13];
    const float* pb1  = (const float*)d_in[14];
    const float* pw2  = (const float*)d_in[15];
    const float* pb2  = (const float*)d_in[16];
    const float* pw3  = (const float*)d_in[17];
    const float* pb3  = (const float*)d_in[18];
    const float* wih  = (const float*)d_in[19];
    const float* whh  = (const float*)d_in[20];
    const float* bihp = (const float*)d_in[21];
    const float* bhhp = (const float*)d_in[22];
    const float* hn0  = (const float*)d_in[23];
    const float* ow   = (const float*)d_in[24];
    const float* ob   = (const float*)d_in[25];
    float* out = (float*)d_out;

    float* c = (float*)d_ws;                                  // 2048 floats
    int*   p = (int*)((char*)d_ws + 2048 * sizeof(float));    // 32 ints

    kAB<<<2048, 192, 0, stream>>>(x, c1w, c1b, bn1g, bn1b, bn1m, bn1v,
                                  c2w, c2b, bn2g, bn2b, bn2m, bn2v, c);
    kC<<<1, 64, 0, stream>>>(c, pw1, pb1, pw2, pb2, pw3, pb3, p);
    kD<<<6, 64, 0, stream>>>(c, p, wih, whh, bihp, bhhp, hn0, ow, ob, out);
}

// Round 2
// 1640.645 us; speedup vs baseline: 2.0545x; 2.0545x over previous
//
#include <hip/hip_runtime.h>

#define EPS 1e-5f

__device__ __forceinline__ float fast_rcp(float x) { return __builtin_amdgcn_rcpf(x); }
__device__ __forceinline__ float sigm(float x) { return fast_rcp(1.f + __expf(-x)); }
__device__ __forceinline__ float tanh_fast(float x) { return 1.f - 2.f * fast_rcp(1.f + __expf(2.f * x)); }
__device__ __forceinline__ float rdlane(float v, int l) {
    return __int_as_float(__builtin_amdgcn_readlane(__float_as_int(v), l));
}

// ---------------------------------------------------------------------------
// Kernel AB: one image per block (2048 blocks, 256 threads).
// Stage A: conv1(3->16,4x4,s4)+bn+relu+pool3 -> plds[16][12][13(pad)]
//   Thread <-> conv output position (oy,ox). Lane-consecutive ox => loads are
//   runs of consecutive float4 (stride-4 width-4 conv partitions rows into
//   aligned float4s; each x byte read exactly once, fully coalesced).
//   Weights broadcast from LDS (same-address b128 = conflict-free broadcast).
// Stage B: conv2(16->1,4x4,s4)+bn+relu+pool3 -> c[img] (wave 0).
// ---------------------------------------------------------------------------
__global__ __launch_bounds__(256, 4) void kAB(
    const float* __restrict__ x,
    const float* __restrict__ w1, const float* __restrict__ cb1,
    const float* __restrict__ g1, const float* __restrict__ b1,
    const float* __restrict__ m1, const float* __restrict__ v1,
    const float* __restrict__ w2, const float* __restrict__ cb2,
    const float* __restrict__ g2, const float* __restrict__ b2,
    const float* __restrict__ m2, const float* __restrict__ v2,
    float* __restrict__ c)
{
    __shared__ __align__(16) float wlds[12][16][4];   // [q=(ci,dy)][co][kx]
    __shared__ float sc[16], sh[16];
    __shared__ float convbuf[6][36][17];              // conv rows for one pp, pad 17
    __shared__ float plds[16][12][13];                // pooled stage-A out, pad 13

    const int tid = threadIdx.x;
    const int img = blockIdx.x;
    const float* xb = x + (size_t)img * 62208;        // 3*144*144

    if (tid < 16) {
        float s = g1[tid] * rsqrtf(v1[tid] + EPS);
        sc[tid] = s;
        sh[tid] = b1[tid] + (cb1[tid] - m1[tid]) * s;
    }
    if (tid < 192) {  // transpose conv1 weights: wlds[q][co][*] = w1[co][q*4..]
        const int co = tid & 15, q = tid >> 4;
        *(float4*)wlds[q][co] = *(const float4*)(w1 + co * 48 + q * 4);
    }
    __syncthreads();

    for (int pp = 0; pp < 6; ++pp) {   // 6 double-pool-row strips (6 conv rows each)
        if (tid < 216) {
            const int ox = tid % 36;
            const int ry = tid / 36;                  // 0..5
            const int oy = pp * 6 + ry;
            const float* pbase = xb + oy * 576 + ox * 4;   // (4*oy)*144 + 4*ox
            float4 patch[12];
#pragma unroll
            for (int ci = 0; ci < 3; ++ci)
#pragma unroll
                for (int dy = 0; dy < 4; ++dy)
                    patch[ci * 4 + dy] = *(const float4*)(pbase + ci * 20736 + dy * 144);
            float acc[16];
#pragma unroll
            for (int co = 0; co < 16; ++co) acc[co] = 0.f;
#pragma unroll
            for (int q = 0; q < 12; ++q) {
                const float4 pq = patch[q];
#pragma unroll
                for (int co = 0; co < 16; ++co) {
                    const float4 wv = *(const float4*)wlds[q][co];  // broadcast
                    acc[co] = fmaf(pq.x, wv.x,
                              fmaf(pq.y, wv.y,
                              fmaf(pq.z, wv.z,
                              fmaf(pq.w, wv.w, acc[co]))));
                }
            }
#pragma unroll
            for (int co = 0; co < 16; ++co)
                convbuf[ry][ox][co] = fmaxf(fmaf(acc[co], sc[co], sh[co]), 0.f);
        }
        __syncthreads();
        // pool 3x3: items (pr in 2, px in 12, co in 16) = 384
        for (int i = tid; i < 384; i += 256) {
            const int pr = i & 1;
            const int px = (i >> 1) % 12;
            const int co = i / 24;
            float best = 0.f;
#pragma unroll
            for (int dy = 0; dy < 3; ++dy)
#pragma unroll
                for (int dx = 0; dx < 3; ++dx)
                    best = fmaxf(best, convbuf[pr * 3 + dy][px * 3 + dx][co]);
            plds[co][pp * 2 + pr][px] = best;
        }
        __syncthreads();
    }

    // Stage B on wave 0: conv2 over plds. lane = (ch, dy)
    if (tid < 64) {
        const int ch = tid >> 2, dy = tid & 3;
        const float4 wv = *(const float4*)(w2 + ch * 16 + dy * 4);
        const float scale = g2[0] * rsqrtf(v2[0] + EPS);
        const float shift = b2[0] + (cb2[0] - m2[0]) * scale;
        float best = 0.f;
#pragma unroll
        for (int oy = 0; oy < 3; ++oy)
#pragma unroll
            for (int ox = 0; ox < 3; ++ox) {
                const float* ab = &plds[ch][4 * oy + dy][4 * ox];
                float s = ab[0] * wv.x + ab[1] * wv.y + ab[2] * wv.z + ab[3] * wv.w;
#pragma unroll
                for (int off = 32; off >= 1; off >>= 1) s += __shfl_xor(s, off);
                float val = fmaxf(fmaf(s, scale, shift), 0.f);
                best = fmaxf(best, val);
            }
        if (tid == 0) c[img] = best;
    }
}

// ---------------------------------------------------------------------------
// Kernel C: gating MLP + argmax -> expert index p[32]. One wave, thread=sample.
// ---------------------------------------------------------------------------
__global__ __launch_bounds__(64) void kC(
    const float* __restrict__ c,
    const float* __restrict__ w1, const float* __restrict__ b1,
    const float* __restrict__ w2, const float* __restrict__ b2,
    const float* __restrict__ w3, const float* __restrict__ b3,
    int* __restrict__ p)
{
    const int b = threadIdx.x;
    if (b >= 32) return;
    const float* cb = c + b * 64;
    float h1[32];
#pragma unroll
    for (int j = 0; j < 32; ++j) {
        float s = b1[j];
        for (int i = 0; i < 64; ++i) s = fmaf(w1[j * 64 + i], cb[i], s);
        h1[j] = tanhf(s);
    }
    float h2[32];
#pragma unroll
    for (int j = 0; j < 32; ++j) {
        float s = b2[j];
#pragma unroll
        for (int i = 0; i < 32; ++i) s = fmaf(w2[j * 32 + i], h1[i], s);
        h2[j] = tanhf(s);
    }
    float best = -3.4e38f;
    int bi = 0;
#pragma unroll
    for (int j = 0; j < 6; ++j) {
        float s = b3[j];
#pragma unroll
        for (int i = 0; i < 32; ++i) s = fmaf(w3[j * 32 + i], h2[i], s);
        if (s > best) { best = s; bi = j; }  // strict > == first-max (jnp.argmax)
    }
    p[b] = bi;
}

// ---------------------------------------------------------------------------
// Kernel D: per-expert LSTM chain, 6 blocks x 1 wave, PURE VALU inner loop.
// Lane k (duplicated in both wave halves, k = lane&31) owns hidden unit k and
// computes ALL FOUR gate rows (k, k+32, k+64, k+96) with whh rows pinned in
// 128 VGPRs. All broadcasts are v_readlane (SGPR), zero LDS/bpermute ops.
// ---------------------------------------------------------------------------
__global__ __launch_bounds__(64, 1) void kD(
    const float* __restrict__ c, const int* __restrict__ p,
    const float* __restrict__ wih, const float* __restrict__ whh,
    const float* __restrict__ bih, const float* __restrict__ bhh,
    const float* __restrict__ hn0,
    const float* __restrict__ ow, const float* __restrict__ obias,
    float* __restrict__ out)
{
    const int e = blockIdx.x;
    const int lane = threadIdx.x;   // 0..63
    const int k = lane & 31;
    const float* we = whh + e * 4096;  // [128][32]
    float wI[32], wF[32], wG[32], wO[32];
#pragma unroll
    for (int j4 = 0; j4 < 8; ++j4) {
        *(float4*)&wI[j4 * 4] = *(const float4*)(we + (k)      * 32 + j4 * 4);
        *(float4*)&wF[j4 * 4] = *(const float4*)(we + (k + 32) * 32 + j4 * 4);
        *(float4*)&wG[j4 * 4] = *(const float4*)(we + (k + 64) * 32 + j4 * 4);
        *(float4*)&wO[j4 * 4] = *(const float4*)(we + (k + 96) * 32 + j4 * 4);
    }
    const float wiI = wih[e * 128 + k],      wiF = wih[e * 128 + k + 32];
    const float wiG = wih[e * 128 + k + 64], wiO = wih[e * 128 + k + 96];
    const float bI = bih[e * 128 + k]      + bhh[e * 128 + k];
    const float bF = bih[e * 128 + k + 32] + bhh[e * 128 + k + 32];
    const float bG = bih[e * 128 + k + 64] + bhh[e * 128 + k + 64];
    const float bO = bih[e * 128 + k + 96] + bhh[e * 128 + k + 96];
    float h = hn0[e * 32 + k];   // chain state (both halves identical)

    for (int b = 0; b < 32; ++b) {
        if (p[b] != e) continue;  // wave-uniform
        const float cvec = c[b * 64 + lane];
        float cc = 0.f;           // cell state resets per sample
        float rvec = 0.f;         // lane t holds r_t = h_t[31]
        for (int t = 0; t < 64; ++t) {
            const float xt = rdlane(cvec, t);
            float aI = fmaf(wiI, xt, bI);
            float aF = fmaf(wiF, xt, bF);
            float aG = fmaf(wiG, xt, bG);
            float aO = fmaf(wiO, xt, bO);
#pragma unroll
            for (int j = 0; j < 32; ++j) {
                const float hj = rdlane(h, j);
                aI = fmaf(wI[j], hj, aI);
                aF = fmaf(wF[j], hj, aF);
                aG = fmaf(wG[j], hj, aG);
                aO = fmaf(wO[j], hj, aO);
            }
            const float ig = sigm(aI), fg = sigm(aF);
            const float gg = tanh_fast(aG), og = sigm(aO);
            cc = fmaf(fg, cc, ig * gg);
            h = og * tanh_fast(cc);
            const float h31 = rdlane(h, 31);
            rvec = (lane == t) ? h31 : rvec;
        }
#pragma unroll
        for (int a = 0; a < 6; ++a) {
            float tsum = rvec * ow[a * 64 + lane];
#pragma unroll
            for (int off = 32; off >= 1; off >>= 1) tsum += __shfl_xor(tsum, off);
            if (lane == 0) out[b * 6 + a] = tsum + obias[a];
        }
    }
}

extern "C" void kernel_launch(void* const* d_in, const int* in_sizes, int n_in,
                              void* d_out, int out_size, void* d_ws, size_t ws_size,
                              hipStream_t stream)
{
    const float* x    = (const float*)d_in[0];
    const float* c1w  = (const float*)d_in[1];
    const float* c1b  = (const float*)d_in[2];
    const float* bn1g = (const float*)d_in[3];
    const float* bn1b = (const float*)d_in[4];
    const float* bn1m = (const float*)d_in[5];
    const float* bn1v = (const float*)d_in[6];
    const float* c2w  = (const float*)d_in[7];
    const float* c2b  = (const float*)d_in[8];
    const float* bn2g = (const float*)d_in[9];
    const float* bn2b = (const float*)d_in[10];
    const float* bn2m = (const float*)d_in[11];
    const float* bn2v = (const float*)d_in[12];
    const float* pw1  = (const float*)d_in[13];
    const float* pb1  = (const float*)d_in[14];
    const float* pw2  = (const float*)d_in[15];
    const float* pb2  = (const float*)d_in[16];
    const float* pw3  = (const float*)d_in[17];
    const float* pb3  = (const float*)d_in[18];
    const float* wih  = (const float*)d_in[19];
    const float* whh  = (const float*)d_in[20];
    const float* bihp = (const float*)d_in[21];
    const float* bhhp = (const float*)d_in[22];
    const float* hn0  = (const float*)d_in[23];
    const float* ow   = (const float*)d_in[24];
    const float* ob   = (const float*)d_in[25];
    float* out = (float*)d_out;

    float* c = (float*)d_ws;                                  // 2048 floats
    int*   p = (int*)((char*)d_ws + 2048 * sizeof(float));    // 32 ints

    kAB<<<2048, 256, 0, stream>>>(x, c1w, c1b, bn1g, bn1b, bn1m, bn1v,
                                  c2w, c2b, bn2g, bn2b, bn2m, bn2v, c);
    kC<<<1, 64, 0, stream>>>(c, pw1, pb1, pw2, pb2, pw3, pb3, p);
    kD<<<6, 64, 0, stream>>>(c, p, wih, whh, bihp, bhhp, hn0, ow, ob, out);
}

// Round 3
// 1424.470 us; speedup vs baseline: 2.3663x; 1.1518x over previous
//
#include <hip/hip_runtime.h>

#define EPS 1e-5f

__device__ __forceinline__ float fast_rcp(float x) { return __builtin_amdgcn_rcpf(x); }
__device__ __forceinline__ float sigm(float x) { return fast_rcp(1.f + __expf(-x)); }
__device__ __forceinline__ float tanh_fast(float x) { return 1.f - 2.f * fast_rcp(1.f + __expf(2.f * x)); }
__device__ __forceinline__ float rdlane(float v, int l) {
    return __int_as_float(__builtin_amdgcn_readlane(__float_as_int(v), l));
}

// ---------------------------------------------------------------------------
// Kernel AB: one image per block (2048 blocks, 256 threads).
// Conv1 weights are WAVE-UNIFORM: accessed from global with compile-time
// constant indices -> compiler emits s_load into SGPRs; each FMA uses the
// weight as its single SGPR operand. Zero DS traffic in the MAC loop
// (R2 was DS-issue-bound: 192 ds_read_b128 per output position).
// ---------------------------------------------------------------------------
__global__ __launch_bounds__(256, 4) void kAB(
    const float* __restrict__ x,
    const float* __restrict__ w1, const float* __restrict__ cb1,
    const float* __restrict__ g1, const float* __restrict__ b1,
    const float* __restrict__ m1, const float* __restrict__ v1,
    const float* __restrict__ w2, const float* __restrict__ cb2,
    const float* __restrict__ g2, const float* __restrict__ b2,
    const float* __restrict__ m2, const float* __restrict__ v2,
    float* __restrict__ c)
{
    __shared__ float sc[16], sh[16];
    __shared__ float convbuf[6][36][17];   // conv rows for one strip, pad 17
    __shared__ float plds[16][12][13];     // pooled stage-A out, pad 13

    const int tid = threadIdx.x;
    const int img = blockIdx.x;
    const float* xb = x + (size_t)img * 62208;  // 3*144*144

    if (tid < 16) {
        float s = g1[tid] * rsqrtf(v1[tid] + EPS);
        sc[tid] = s;
        sh[tid] = b1[tid] + (cb1[tid] - m1[tid]) * s;
    }
    __syncthreads();

    for (int pp = 0; pp < 6; ++pp) {   // 6 strips of 6 conv rows (=2 pool rows)
        if (tid < 216) {
            const int ox = tid % 36;
            const int ry = tid / 36;                  // 0..5
            const int oy = pp * 6 + ry;
            const float* pbase = xb + oy * 576 + ox * 4;
            float4 patch[12];
#pragma unroll
            for (int ci = 0; ci < 3; ++ci)
#pragma unroll
                for (int dy = 0; dy < 4; ++dy)
                    patch[ci * 4 + dy] = *(const float4*)(pbase + ci * 20736 + dy * 144);
            float acc[16];
#pragma unroll
            for (int co = 0; co < 16; ++co) acc[co] = 0.f;
#pragma unroll
            for (int q = 0; q < 12; ++q) {
                const float4 pq = patch[q];
#pragma unroll
                for (int co = 0; co < 16; ++co) {
                    const float* wp = w1 + co * 48 + q * 4;   // uniform -> s_load
                    acc[co] = fmaf(pq.x, wp[0],
                              fmaf(pq.y, wp[1],
                              fmaf(pq.z, wp[2],
                              fmaf(pq.w, wp[3], acc[co]))));
                }
            }
#pragma unroll
            for (int co = 0; co < 16; ++co)
                convbuf[ry][ox][co] = fmaxf(fmaf(acc[co], sc[co], sh[co]), 0.f);
        }
        __syncthreads();
        // pool 3x3: items (pr in 2, px in 12, co in 16) = 384
        for (int i = tid; i < 384; i += 256) {
            const int pr = i & 1;
            const int px = (i >> 1) % 12;
            const int co = i / 24;
            float best = 0.f;
#pragma unroll
            for (int dy = 0; dy < 3; ++dy)
#pragma unroll
                for (int dx = 0; dx < 3; ++dx)
                    best = fmaxf(best, convbuf[pr * 3 + dy][px * 3 + dx][co]);
            plds[co][pp * 2 + pr][px] = best;
        }
        __syncthreads();
    }

    // Stage B on wave 0: conv2 over plds. lane = (ch, dy)
    if (tid < 64) {
        const int ch = tid >> 2, dy = tid & 3;
        const float4 wv = *(const float4*)(w2 + ch * 16 + dy * 4);
        const float scale = g2[0] * rsqrtf(v2[0] + EPS);
        const float shift = b2[0] + (cb2[0] - m2[0]) * scale;
        float best = 0.f;
#pragma unroll
        for (int oy = 0; oy < 3; ++oy)
#pragma unroll
            for (int ox = 0; ox < 3; ++ox) {
                const float* ab = &plds[ch][4 * oy + dy][4 * ox];
                float s = ab[0] * wv.x + ab[1] * wv.y + ab[2] * wv.z + ab[3] * wv.w;
#pragma unroll
                for (int off = 32; off >= 1; off >>= 1) s += __shfl_xor(s, off);
                float val = fmaxf(fmaf(s, scale, shift), 0.f);
                best = fmaxf(best, val);
            }
        if (tid == 0) c[img] = best;
    }
}

// ---------------------------------------------------------------------------
// Kernel C: gating MLP + argmax -> expert index p[32]. One wave, thread=sample.
// ---------------------------------------------------------------------------
__global__ __launch_bounds__(64) void kC(
    const float* __restrict__ c,
    const float* __restrict__ w1, const float* __restrict__ b1,
    const float* __restrict__ w2, const float* __restrict__ b2,
    const float* __restrict__ w3, const float* __restrict__ b3,
    int* __restrict__ p)
{
    const int b = threadIdx.x;
    if (b >= 32) return;
    const float* cb = c + b * 64;
    float h1[32];
#pragma unroll
    for (int j = 0; j < 32; ++j) {
        float s = b1[j];
        for (int i = 0; i < 64; ++i) s = fmaf(w1[j * 64 + i], cb[i], s);
        h1[j] = tanhf(s);
    }
    float h2[32];
#pragma unroll
    for (int j = 0; j < 32; ++j) {
        float s = b2[j];
#pragma unroll
        for (int i = 0; i < 32; ++i) s = fmaf(w2[j * 32 + i], h1[i], s);
        h2[j] = tanhf(s);
    }
    float best = -3.4e38f;
    int bi = 0;
#pragma unroll
    for (int j = 0; j < 6; ++j) {
        float s = b3[j];
#pragma unroll
        for (int i = 0; i < 32; ++i) s = fmaf(w3[j * 32 + i], h2[i], s);
        if (s > best) { best = s; bi = j; }  // strict > == first-max (jnp.argmax)
    }
    p[b] = bi;
}

// ---------------------------------------------------------------------------
// Kernel D: per-expert LSTM chain, 6 blocks x 1 wave, pure-VALU inner loop.
// Lane k (k = lane&31, duplicated in both halves) owns hidden unit k and
// computes all four gate rows. whh rows held in float4 ARRAYS with constant
// indices only (no type-puns on locals) so SROA promotes them to ~128 VGPRs.
// All broadcasts are v_readlane. Two partial accumulators per gate.
// ---------------------------------------------------------------------------
__global__ __launch_bounds__(64, 1) void kD(
    const float* __restrict__ c, const int* __restrict__ p,
    const float* __restrict__ wih, const float* __restrict__ whh,
    const float* __restrict__ bih, const float* __restrict__ bhh,
    const float* __restrict__ hn0,
    const float* __restrict__ ow, const float* __restrict__ obias,
    float* __restrict__ out)
{
    const int e = blockIdx.x;
    const int lane = threadIdx.x;   // 0..63
    const int k = lane & 31;
    const float* we = whh + e * 4096;  // [128][32]

    float4 wI4[8], wF4[8], wG4[8], wO4[8];
#pragma unroll
    for (int j = 0; j < 8; ++j) {
        wI4[j] = *(const float4*)(we + (k)      * 32 + j * 4);
        wF4[j] = *(const float4*)(we + (k + 32) * 32 + j * 4);
        wG4[j] = *(const float4*)(we + (k + 64) * 32 + j * 4);
        wO4[j] = *(const float4*)(we + (k + 96) * 32 + j * 4);
    }
    const float wiI = wih[e * 128 + k],      wiF = wih[e * 128 + k + 32];
    const float wiG = wih[e * 128 + k + 64], wiO = wih[e * 128 + k + 96];
    const float bI = bih[e * 128 + k]      + bhh[e * 128 + k];
    const float bF = bih[e * 128 + k + 32] + bhh[e * 128 + k + 32];
    const float bG = bih[e * 128 + k + 64] + bhh[e * 128 + k + 64];
    const float bO = bih[e * 128 + k + 96] + bhh[e * 128 + k + 96];
    float h = hn0[e * 32 + k];   // chain state

    for (int b = 0; b < 32; ++b) {
        if (p[b] != e) continue;  // wave-uniform
        const float cvec = c[b * 64 + lane];
        float cc = 0.f;
        float rvec = 0.f;         // lane t holds r_t = h_t[31]
        for (int t = 0; t < 64; ++t) {
            const float xt = rdlane(cvec, t);
            float aI0 = fmaf(wiI, xt, bI), aI1 = 0.f;
            float aF0 = fmaf(wiF, xt, bF), aF1 = 0.f;
            float aG0 = fmaf(wiG, xt, bG), aG1 = 0.f;
            float aO0 = fmaf(wiO, xt, bO), aO1 = 0.f;
#pragma unroll
            for (int j = 0; j < 8; ++j) {
                const float h0 = rdlane(h, 4 * j + 0);
                const float h1 = rdlane(h, 4 * j + 1);
                const float h2 = rdlane(h, 4 * j + 2);
                const float h3 = rdlane(h, 4 * j + 3);
                aI0 = fmaf(wI4[j].x, h0, aI0); aI1 = fmaf(wI4[j].y, h1, aI1);
                aI0 = fmaf(wI4[j].z, h2, aI0); aI1 = fmaf(wI4[j].w, h3, aI1);
                aF0 = fmaf(wF4[j].x, h0, aF0); aF1 = fmaf(wF4[j].y, h1, aF1);
                aF0 = fmaf(wF4[j].z, h2, aF0); aF1 = fmaf(wF4[j].w, h3, aF1);
                aG0 = fmaf(wG4[j].x, h0, aG0); aG1 = fmaf(wG4[j].y, h1, aG1);
                aG0 = fmaf(wG4[j].z, h2, aG0); aG1 = fmaf(wG4[j].w, h3, aG1);
                aO0 = fmaf(wO4[j].x, h0, aO0); aO1 = fmaf(wO4[j].y, h1, aO1);
                aO0 = fmaf(wO4[j].z, h2, aO0); aO1 = fmaf(wO4[j].w, h3, aO1);
            }
            const float ig = sigm(aI0 + aI1), fg = sigm(aF0 + aF1);
            const float gg = tanh_fast(aG0 + aG1), og = sigm(aO0 + aO1);
            cc = fmaf(fg, cc, ig * gg);
            h = og * tanh_fast(cc);
            const float h31 = rdlane(h, 31);
            rvec = (lane == t) ? h31 : rvec;
        }
#pragma unroll
        for (int a = 0; a < 6; ++a) {
            float tsum = rvec * ow[a * 64 + lane];
#pragma unroll
            for (int off = 32; off >= 1; off >>= 1) tsum += __shfl_xor(tsum, off);
            if (lane == 0) out[b * 6 + a] = tsum + obias[a];
        }
    }
}

extern "C" void kernel_launch(void* const* d_in, const int* in_sizes, int n_in,
                              void* d_out, int out_size, void* d_ws, size_t ws_size,
                              hipStream_t stream)
{
    const float* x    = (const float*)d_in[0];
    const float* c1w  = (const float*)d_in[1];
    const float* c1b  = (const float*)d_in[2];
    const float* bn1g = (const float*)d_in[3];
    const float* bn1b = (const float*)d_in[4];
    const float* bn1m = (const float*)d_in[5];
    const float* bn1v = (const float*)d_in[6];
    const float* c2w  = (const float*)d_in[7];
    const float* c2b  = (const float*)d_in[8];
    const float* bn2g = (const float*)d_in[9];
    const float* bn2b = (const float*)d_in[10];
    const float* bn2m = (const float*)d_in[11];
    const float* bn2v = (const float*)d_in[12];
    const float* pw1  = (const float*)d_in[13];
    const float* pb1  = (const float*)d_in[14];
    const float* pw2  = (const float*)d_in[15];
    const float* pb2  = (const float*)d_in[16];
    const float* pw3  = (const float*)d_in[17];
    const float* pb3  = (const float*)d_in[18];
    const float* wih  = (const float*)d_in[19];
    const float* whh  = (const float*)d_in[20];
    const float* bihp = (const float*)d_in[21];
    const float* bhhp = (const float*)d_in[22];
    const float* hn0  = (const float*)d_in[23];
    const float* ow   = (const float*)d_in[24];
    const float* ob   = (const float*)d_in[25];
    float* out = (float*)d_out;

    float* c = (float*)d_ws;                                  // 2048 floats
    int*   p = (int*)((char*)d_ws + 2048 * sizeof(float));    // 32 ints

    kAB<<<2048, 256, 0, stream>>>(x, c1w, c1b, bn1g, bn1b, bn1m, bn1v,
                                  c2w, c2b, bn2g, bn2b, bn2m, bn2v, c);
    kC<<<1, 64, 0, stream>>>(c, pw1, pb1, pw2, pb2, pw3, pb3, p);
    kD<<<6, 64, 0, stream>>>(c, p, wih, whh, bihp, bhhp, hn0, ow, ob, out);
}